// Round 6
// baseline (365.056 us; speedup 1.0000x reference)
//
#include <hip/hip_runtime.h>
#include <cstdint>
#include <cstddef>

#define M_DIM 4096
#define K_DIM 4096
#define N_DIM 11008
#define BM 256
#define BN 256
#define BKB 128                       /* K bytes per K-tile (2 slices of 64) */
#define NT (K_DIM / BKB)              /* 32 K-tiles */
#define NTM (M_DIM / BM)              /* 16 */
#define NTN (N_DIM / BN)              /* 43 */
#define SLOT_BYTES 65536              /* A 32KB + B 32KB */
#define B_OFF 32768

typedef int   int4v   __attribute__((ext_vector_type(4)));
typedef float float4v __attribute__((ext_vector_type(4)));

__device__ __forceinline__ void gload_lds16(const void* g, void* l) {
  __builtin_amdgcn_global_load_lds(
      (const __attribute__((address_space(1))) unsigned int*)g,
      (__attribute__((address_space(3))) unsigned int*)l, 16, 0, 0);
}

// ---------------- x quantization: fp32 -> int8 ----------------
__global__ void quant_x_kernel(const float* __restrict__ x,
                               const float* __restrict__ scale_p,
                               const int* __restrict__ off_p,
                               signed char* __restrict__ xq, int total16) {
  const float inv = 1.0f / scale_p[0];
  const float off = (float)off_p[0];
  int tid = blockIdx.x * blockDim.x + threadIdx.x;
  int stride = gridDim.x * blockDim.x;
  const float4v* x4 = (const float4v*)x;
  int4v* out4 = (int4v*)xq;
  for (int i = tid; i < total16; i += stride) {
    int4v o;
#pragma unroll
    for (int j = 0; j < 4; ++j) {
      float4v v = x4[(size_t)i * 4 + j];
      int r = 0;
#pragma unroll
      for (int e = 0; e < 4; ++e) {
        float q = rintf(v[e] * inv) + off;     // round-half-even, matches jnp.round
        q = fminf(fmaxf(q, -128.0f), 127.0f);
        int qi = (int)q;
        r |= (qi & 0xff) << (8 * e);
      }
      o[j] = r;
    }
    out4[i] = o;
  }
}

// ---------------- weight pack: int32 carrier -> int8 ----------------
__global__ void pack_w_kernel(const int* __restrict__ w,
                              signed char* __restrict__ wq, int total16) {
  int tid = blockIdx.x * blockDim.x + threadIdx.x;
  int stride = gridDim.x * blockDim.x;
  const int4v* w4 = (const int4v*)w;
  int4v* out4 = (int4v*)wq;
  for (int i = tid; i < total16; i += stride) {
    int4v o;
#pragma unroll
    for (int j = 0; j < 4; ++j) {
      int4v v = w4[(size_t)i * 4 + j];
      o[j] = (v[0] & 0xff) | ((v[1] & 0xff) << 8) |
             ((v[2] & 0xff) << 16) | ((v[3] & 0xff) << 24);
    }
    out4[i] = o;
  }
}

// ------ int8 GEMM: 256x256 tile, 4 waves x (128x128/wave), 1 barrier/K-tile ------
// A: xq [M][K] int8, B: wq [N][K] int8 (B^T), out fp32 [M][N]
// LDS fragment-packed (0 bank conflicts, verified R2-R5): frag(rg,ks) = 1 KB
// holding rows rg*16..+15, K bytes ks*64..+63; lane l's 16B at frag*1024+l*16
// = [rg*16+(l&15)][ks*64+(l>>4)*16 ..+16].  A frags at (rg*2+ks)*1024, B at
// B_OFF + same.  Double-buffer slot = (kt&1)*64KB.
// Per-wave private pipeline inside a tile; ONE s_barrier per K-tile.
__global__ __launch_bounds__(256, 1) void gemm_i8_kernel(
    const signed char* __restrict__ A,
    const signed char* __restrict__ B,
    const int* __restrict__ qbias,
    const float* __restrict__ dscale,
    float* __restrict__ out) {
  __shared__ __attribute__((aligned(16))) signed char lds[2 * SLOT_BYTES];  // 128 KB

  const int tid  = threadIdx.x;
  const int lane = tid & 63;
  const int wv   = tid >> 6;   // 0..3
  const int wr   = wv >> 1;    // 0..1  (M half: 128 rows)
  const int wc   = wv & 1;     // 0..1  (N half: 128 cols)

  // XCD swizzle: 688 blocks, 86/XCD; xcd x owns tm {2x,2x+1}, tm-paired so the
  // two blocks sharing a B-panel are dispatch-adjacent (L2 reuse).
  int bid = blockIdx.x;
  int s   = bid >> 3;                 // 0..85
  int tm  = 2 * (bid & 7) + (s & 1);  // 0..15
  int tn  = s >> 1;                   // 0..42

  // ---- staging: wave wv owns A/B row-groups rg = wv*4+c (c=0..3), ks=0..1 ----
  const signed char* pA = A + (size_t)(tm * BM + wv * 64 + (lane & 15)) * K_DIM
                            + (lane >> 4) * 16;
  const signed char* pB = B + (size_t)(tn * BN + wv * 64 + (lane & 15)) * K_DIM
                            + (lane >> 4) * 16;

#define STG(kt, so) do {                                                      \
    _Pragma("unroll") for (int c = 0; c < 4; ++c)                             \
      _Pragma("unroll") for (int ks = 0; ks < 2; ++ks) {                      \
        gload_lds16(pA + (size_t)c * 16 * K_DIM + (size_t)(kt) * BKB + ks * 64, \
                    lds + (so) + ((((wv * 4 + c) * 2 + ks)) << 10));          \
        gload_lds16(pB + (size_t)c * 16 * K_DIM + (size_t)(kt) * BKB + ks * 64, \
                    lds + (so) + B_OFF + ((((wv * 4 + c) * 2 + ks)) << 10));  \
      } } while (0)

  // ---- ds_read: wave's A frags rg = wr*8+m, B frags rg = wc*8+n ----
#define RD_A(buf, so, ks) do {                                                \
    _Pragma("unroll") for (int m = 0; m < 8; ++m)                             \
      buf[m] = *(const int4v*)(lds + (so) +                                   \
                (((wr * 8 + m) * 2 + (ks)) << 10) + lane * 16); } while (0)
#define RD_B(buf, so, ks) do {                                                \
    _Pragma("unroll") for (int n = 0; n < 8; ++n)                             \
      buf[n] = *(const int4v*)(lds + (so) + B_OFF +                           \
                (((wc * 8 + n) * 2 + (ks)) << 10) + lane * 16); } while (0)
#define MFMA_S(ab, bb) do {                                                   \
    _Pragma("unroll") for (int m = 0; m < 8; ++m)                             \
      _Pragma("unroll") for (int n = 0; n < 8; ++n)                           \
        acc[m][n] = __builtin_amdgcn_mfma_i32_16x16x64_i8(                    \
            ab[m], bb[n], acc[m][n], 0, 0, 0); } while (0)
#define WAIT_LGKM(k) do {                                                     \
    asm volatile("s_waitcnt lgkmcnt(" #k ")" ::: "memory");                   \
    __builtin_amdgcn_sched_barrier(0); } while (0)

  int4v acc[8][8];
#pragma unroll
  for (int i = 0; i < 8; ++i)
#pragma unroll
    for (int j = 0; j < 8; ++j) acc[i][j] = (int4v){0, 0, 0, 0};

  int4v A0[8], A1[8], B0[8], B1[8];

  // ---- prologue: stage tiles 0,1; read slice0 of tile0 ----
  STG(0, 0);
  STG(1, SLOT_BYTES);
  asm volatile("s_waitcnt vmcnt(16)" ::: "memory");  // tile 0 landed
  __builtin_amdgcn_s_barrier();
  __builtin_amdgcn_sched_barrier(0);
  RD_A(A0, 0, 0);
  RD_B(B0, 0, 0);                                    // 16 lgkm outstanding

  for (int kt = 0; kt < NT; ++kt) {
    const int cur = (kt & 1) * SLOT_BYTES;
    const int nxt = cur ^ SLOT_BYTES;

    RD_A(A1, cur, 1);          // 8 reads (slice 1 A)
    WAIT_LGKM(8);              // A0,B0 complete (older than A1's 8)
    RD_B(B1, cur, 1);          // 8 reads (slice 1 B) -> execute under MFMA s0
    MFMA_S(A0, B0);            // slice 0: 64 MFMA (~1300 cyc)
    WAIT_LGKM(8);              // A1 complete (done during MFMA s0)
    asm volatile("s_waitcnt vmcnt(0)" ::: "memory");  // tile kt+1 (mine) landed
    WAIT_LGKM(0);              // B1 complete; ALL my cur-slot reads done
    __builtin_amdgcn_s_barrier();   // everyone done with cur; kt+1 landed for all
    __builtin_amdgcn_sched_barrier(0);
    if (kt + 2 < NT) STG(kt + 2, cur);   // overwrite cur (safe after barrier)
    if (kt + 1 < NT) {
      RD_A(A0, nxt, 0);        // read-ahead slice0 of tile kt+1
      RD_B(B0, nxt, 0);        // -> execute under MFMA s1
    }
    MFMA_S(A1, B1);            // slice 1: 64 MFMA
  }
#undef WAIT_LGKM
#undef MFMA_S
#undef RD_B
#undef RD_A
#undef STG

  // ---- epilogue: out[m][n] = (acc + qbias[n]) * dscale[n] ----
  const int col = lane & 15;
  const int rb  = (lane >> 4) * 4;
  const int gm0 = tm * BM + wr * 128;
  const int gn0 = tn * BN + wc * 128;
#pragma unroll
  for (int n = 0; n < 8; ++n) {
    int gn = gn0 + n * 16 + col;
    float ds = dscale[gn];
    int qb = qbias[gn];
#pragma unroll
    for (int m = 0; m < 8; ++m) {
      int gm = gm0 + m * 16 + rb;
#pragma unroll
      for (int j = 0; j < 4; ++j)
        out[(size_t)(gm + j) * N_DIM + gn] = (float)(acc[m][n][j] + qb) * ds;
    }
  }
}

extern "C" void kernel_launch(void* const* d_in, const int* in_sizes, int n_in,
                              void* d_out, int out_size, void* d_ws, size_t ws_size,
                              hipStream_t stream) {
  const float* x      = (const float*)d_in[0];
  const int*   w      = (const int*)d_in[1];
  const float* dscale = (const float*)d_in[2];
  const float* iscale = (const float*)d_in[3];
  const int*   ioff   = (const int*)d_in[4];
  const int*   qbias  = (const int*)d_in[5];
  float* out = (float*)d_out;

  const size_t xq_bytes = (size_t)M_DIM * K_DIM;        // 16 MB
  const size_t wq_bytes = (size_t)N_DIM * K_DIM;        // 45 MB
  if (ws_size < xq_bytes + wq_bytes) return;

  signed char* xq = (signed char*)d_ws;
  signed char* wq = (signed char*)d_ws + xq_bytes;

  quant_x_kernel<<<2048, 256, 0, stream>>>(x, iscale, ioff, xq, M_DIM * K_DIM / 16);
  pack_w_kernel<<<2048, 256, 0, stream>>>(w, wq, N_DIM * K_DIM / 16);
  gemm_i8_kernel<<<NTM * NTN, 256, 0, stream>>>(xq, wq, qbias, dscale, out);
}